// Round 11
// baseline (353.309 us; speedup 1.0000x reference)
//
#include <hip/hip_runtime.h>
#include <stdint.h>

#define HASH_BUCKETS 1000
#define EMB_DIM 16
#define HDIM 32
#define G4 128   // 4*HDIM
#define TSTEPS 512
#define BATCH 4096

typedef short v8s __attribute__((ext_vector_type(8)));   // 8 bf16 (4 VGPRs)
typedef float v4f __attribute__((ext_vector_type(4)));   // MFMA acc
typedef float v2f __attribute__((ext_vector_type(2)));   // packed f32 pair

__device__ __forceinline__ float frcp(float x) {
    float r; asm("v_rcp_f32 %0, %1" : "=v"(r) : "v"(x)); return r;
}
__device__ __forceinline__ float fexp2(float x) {
    float r; asm("v_exp_f32 %0, %1" : "=v"(r) : "v"(x)); return r;
}
// packed f32->bf16 (RNE): dst.lo16 = bf16(a), dst.hi16 = bf16(b)
__device__ __forceinline__ uint32_t cvtpk_bf16(float a, float b) {
    uint32_t r; asm("v_cvt_pk_bf16_f32 %0, %1, %2" : "=v"(r) : "v"(a), "v"(b)); return r;
}
// f32 -> bf16 (RNE), bits in low 16 (A-build only, once per launch)
__device__ __forceinline__ uint32_t bf16rne(float x) {
    uint32_t u = __float_as_uint(x);
    return (u + 0x7FFFu + ((u >> 16) & 1u)) >> 16;
}

// ---------------------------------------------------------------------------
// Kernel 1 (unchanged): embedding folded through input projection, gate
// exp2-scaling folded in: i/f/o rows x (-log2 e), c-row x (+2 log2 e).
// P2[bucket][h][g] = s_g * sum_e emb[bucket][e] * kernel[e][g*32 + h]
// ---------------------------------------------------------------------------
__global__ void precompute_P2_kernel(const float* __restrict__ emb,
                                     const float* __restrict__ kern,
                                     float* __restrict__ P2) {
    int idx = blockIdx.x * blockDim.x + threadIdx.x;
    if (idx >= HASH_BUCKETS * G4) return;
    int row = idx >> 7;
    int c2  = idx & 127;
    int h = c2 >> 2;
    int g = c2 & 3;
    float acc = 0.f;
#pragma unroll
    for (int e = 0; e < EMB_DIM; ++e)
        acc = fmaf(emb[row * EMB_DIM + e], kern[e * G4 + g * 32 + h], acc);
    float sg = (g == 2) ? 2.8853900817779268f : -1.4426950408889634f;
    P2[idx] = acc * sg;
}

// ---------------------------------------------------------------------------
// Kernel 2: CO-RESIDENT BLOCKS, diagnostic-safe variant.
// r10 (same geometry + raw lgkm-barrier + waves_per_eu(2)) failed absmax by
// 40x despite a pure-function argument that cols 0..7 compute bit-identical
// r9 math (dup cols 8..15 never feed rows 0..7). Suspects: the hand-rolled
// "lgkmcnt(0); s_barrier" (no compiler convergence info) interacting with
// the perturbed schedule, the waves_per_eu attribute, or a corrupted run.
// This round removes BOTH suspects while keeping the co-residency thesis:
//  - real __syncthreads() in the loop (compiler-visible barrier, full drain;
//    drain tax ~free: refill loads are issued ~400cyc before the barrier)
//  - NO waves_per_eu attribute (VGPR 132 naturally admits >=2 blocks/CU;
//    512 blocks -> HW co-schedules 2/CU; independent barriers -> chains
//    drift and fill each other's ~60% idle issue slots)
// Geometry: 512 blocks x 8 real batches; cols 8..15 duplicate cols 0..7
// (wave64 executes the same instruction stream; MFMA needs 16 columns).
// ---------------------------------------------------------------------------
__global__ __launch_bounds__(256)
void lstm_head_kernel(const int* __restrict__ ids,
                      const float* __restrict__ P2,   // [1000][32][4], pre-scaled
                      const float* __restrict__ R,    // rec_kernel [32][128]
                      const float* __restrict__ w1,   // [32][32]
                      const float* __restrict__ b1,   // [32]
                      const float* __restrict__ w2,   // [32]
                      const float* __restrict__ b2,   // [1]
                      float* __restrict__ out) {
    // per col row: hi dwords [0..15] | (legacy lo region, unused) | pad
    __shared__ __align__(16) uint32_t hbuf[2][16][36];
    __shared__ float hfin[16][33];

    const int tid  = threadIdx.x;
    const int w    = tid >> 6;        // wave 0..3
    const int lane = tid & 63;
    const int col  = lane & 15;       // A-fragment row AND hbuf row (16 lanes)
    const int colB = col & 7;         // real batch within the 8-batch block
    const int quad = lane >> 4;       // 0..3
    const int bb   = blockIdx.x * 8;
    const int u0   = 8 * w + 2 * quad;   // adjacent unit pair
    const int u1   = u0 + 1;

    const float PL2E   =  2.8853900817779268f;   // 2*log2(e)
    const float NL2E   = -1.4426950408889634f;
    const float N2PL2E = -5.7707801635558536f;   // -2*PL2E

    // ---- A fragments, plain bf16-RNE (identity k-order: s=2r+e <-> k=8q+s) ----
    union V8 { uint32_t u[4]; v8s v; };
    V8 A0, A1;
    {
        int tt = col >> 2, g = col & 3;
        float sg = (g == 2) ? PL2E : NL2E;
        int gc0 = g * 32 + 8 * w + 2 * tt;
        int gc1 = gc0 + 1;
#pragma unroll
        for (int r = 0; r < 4; ++r) {
            uint32_t h0p[2], h1p[2];
#pragma unroll
            for (int e = 0; e < 2; ++e) {
                int k = quad * 8 + 2 * r + e;
                h0p[e] = bf16rne(R[k * G4 + gc0] * sg);
                h1p[e] = bf16rne(R[k * G4 + gc1] * sg);
            }
            A0.u[r] = h0p[0] | (h0p[1] << 16);
            A1.u[r] = h1p[0] | (h1p[1] << 16);
        }
    }

    for (int i = tid; i < 2 * 16 * 36; i += 256)
        ((uint32_t*)hbuf)[i] = 0u;

    // ---- loop-invariant LDS addresses (conflict-free by analysis) ----
    const uint32_t* rd[2] = { &hbuf[0][col][4 * quad],
                              &hbuf[1][col][4 * quad] };      // Bhi
    uint32_t* wr[2] = { &hbuf[1][col][4 * w + quad],
                        &hbuf[0][col][4 * w + quad] };        // hi

    // ---- xz prefetch: contiguous 32B (units u0,u1 x 4 gates), dist-2,
    //      ping-pong E/O banks, zero moves. Cols 8-15 duplicate colB. ----
    const int* __restrict__ idrow = ids + (size_t)(bb + colB) * TSTEPS;
    const float* __restrict__ baseL = P2 + 4 * u0;   // + id*G4 per step
    v4f xzE0, xzE1, xzO0, xzO1;
    {
        const float* p0 = baseL + (size_t)idrow[0] * G4;
        const float* p1 = baseL + (size_t)idrow[1] * G4;
        xzE0 = *(const v4f*)(p0);
        xzE1 = *(const v4f*)(p0 + 4);
        xzO0 = *(const v4f*)(p1);
        xzO1 = *(const v4f*)(p1 + 4);
    }
    int idE = idrow[2];
    int idO = idrow[3];

    v2f cc = {0.f, 0.f};
    v2f hv2 = {0.f, 0.f};

    __syncthreads();

    union V8R { uint4 q; v8s v; };

#define STEP(PB, XZ0, XZ1, IDX, T)                                              \
    {                                                                           \
        /* B fragment: ONE b128 read IS Bhi (identity k-order) */               \
        V8R Bhi;                                                                \
        Bhi.q = *(const uint4*)(rd[PB]);                                        \
        /* z = R^T h + xz in ONE MFMA per unit (xz rides the C operand) */      \
        v4f z0 = __builtin_amdgcn_mfma_f32_16x16x32_bf16(A0.v, Bhi.v, XZ0, 0, 0, 0); \
        v4f z1 = __builtin_amdgcn_mfma_f32_16x16x32_bf16(A1.v, Bhi.v, XZ1, 0, 0, 0); \
        /* xz banks consumed above -> refill same bank for t+2 (no moves) */    \
        {                                                                       \
            const float* pf_ = baseL + (size_t)(IDX) * G4;                      \
            XZ0 = *(const v4f*)(pf_);                                           \
            XZ1 = *(const v4f*)(pf_ + 4);                                       \
        }                                                                       \
        { int nt_ = (T) + 4; IDX = idrow[nt_ < TSTEPS ? nt_ : (TSTEPS - 1)]; }  \
        /* gates: z pre-scaled, exp2 direct; rcps GROUPED across unit pair */   \
        float ei0 = fexp2(z0[0]), ei1 = fexp2(z1[0]);                           \
        float ef0 = fexp2(z0[1]), ef1 = fexp2(z1[1]);                           \
        float eg0 = fexp2(z0[2]), eg1 = fexp2(z1[2]);                           \
        float eq0 = fexp2(z0[3]), eq1 = fexp2(z1[3]);                           \
        v2f di = v2f{ei0, ei1} + 1.f;                                           \
        v2f df = v2f{ef0, ef1} + 1.f;                                           \
        v2f dc = v2f{eg0, eg1} + 1.f;                                           \
        v2f dq = v2f{eq0, eq1} + 1.f;                                           \
        v2f Pp = di * df, Qq = dc * dq;                                         \
        v2f PQ = Pp * Qq;                                                       \
        float R4 = frcp(PQ.x * PQ.y);                                           \
        v2f rr; rr.x = R4 * PQ.y; rr.y = R4 * PQ.x;                             \
        v2f rP = rr * Qq, rQ = rr * Pp;                                         \
        v2f ig = rP * df, fg = rP * di, rc = rQ * dq, og = rQ * dc;             \
        v2f tz; tz.x = fmaf(N2PL2E, rc.x, PL2E);                                \
                tz.y = fmaf(N2PL2E, rc.y, PL2E);                                \
        v2f itz = ig * tz;                                                      \
        cc.x = fmaf(fg.x, cc.x, itz.x);                                         \
        cc.y = fmaf(fg.y, cc.y, itz.y);                                         \
        float ecc0 = fexp2(cc.x), ecc1 = fexp2(cc.y);                           \
        v2f dn = v2f{ecc0, ecc1} + 1.f;                                         \
        float R2 = frcp(dn.x * dn.y);                                           \
        v2f rn; rn.x = R2 * dn.y; rn.y = R2 * dn.x;                             \
        v2f m2og = og * (-2.f);   /* off-chain (og ready early) */              \
        hv2.x = fmaf(m2og.x, rn.x, og.x);                                       \
        hv2.y = fmaf(m2og.y, rn.y, og.y);                                       \
        /* publish h as plain bf16 pair: ONE cvt_pk + ONE ds_write_b32 */       \
        wr[PB][0] = cvtpk_bf16(hv2.x, hv2.y);                                   \
        /* REAL barrier this round: compiler-visible convergence + drain */     \
        __syncthreads();                                                        \
    }

    for (int t = 0; t < TSTEPS; t += 2) {
        STEP(0, xzE0, xzE1, idE, t)
        STEP(1, xzO0, xzO1, idO, t + 1)
    }
#undef STEP

    // ---- MLP head (8 real batches, single pass) ----
    hfin[col][u0] = hv2.x;
    hfin[col][u1] = hv2.y;
    __syncthreads();

    int u  = tid & 31;
    int bq = tid >> 5;    // 0..7
    {
        float y = b1[u];
#pragma unroll
        for (int k = 0; k < HDIM; ++k)
            y = fmaf(hfin[bq][k], w1[k * HDIM + u], y);
        y = fmaxf(y, 0.f);
        float vv = y * w2[u];
#pragma unroll
        for (int off = 16; off >= 1; off >>= 1)
            vv += __shfl_xor(vv, off);
        if (u == 0) out[bb + bq] = vv + b2[0];
    }
}

extern "C" void kernel_launch(void* const* d_in, const int* in_sizes, int n_in,
                              void* d_out, int out_size, void* d_ws, size_t ws_size,
                              hipStream_t stream) {
    const int*   ids  = (const int*)d_in[0];
    const float* emb  = (const float*)d_in[1];
    const float* kern = (const float*)d_in[2];
    const float* rec  = (const float*)d_in[3];
    const float* w1   = (const float*)d_in[4];
    const float* b1   = (const float*)d_in[5];
    const float* w2   = (const float*)d_in[6];
    const float* b2   = (const float*)d_in[7];
    float* out = (float*)d_out;
    float* P2  = (float*)d_ws;   // 512 KB scratch

    precompute_P2_kernel<<<(HASH_BUCKETS * G4 + 255) / 256, 256, 0, stream>>>(
        emb, kern, P2);
    lstm_head_kernel<<<BATCH / 8, 256, 0, stream>>>(
        ids, P2, rec, w1, b1, w2, b2, out);
}

// Round 12
// 288.339 us; speedup vs baseline: 1.2253x; 1.2253x over previous
//
#include <hip/hip_runtime.h>
#include <stdint.h>

#define HASH_BUCKETS 1000
#define EMB_DIM 16
#define HDIM 32
#define G4 128   // 4*HDIM
#define TSTEPS 512
#define BATCH 4096

typedef short v8s __attribute__((ext_vector_type(8)));   // 8 bf16 (4 VGPRs)
typedef float v4f __attribute__((ext_vector_type(4)));   // MFMA acc
typedef float v2f __attribute__((ext_vector_type(2)));   // packed f32 pair

__device__ __forceinline__ float frcp(float x) {
    float r; asm("v_rcp_f32 %0, %1" : "=v"(r) : "v"(x)); return r;
}
__device__ __forceinline__ float fexp2(float x) {
    float r; asm("v_exp_f32 %0, %1" : "=v"(r) : "v"(x)); return r;
}
// packed f32->bf16 (RNE): dst.lo16 = bf16(a), dst.hi16 = bf16(b)
__device__ __forceinline__ uint32_t cvtpk_bf16(float a, float b) {
    uint32_t r; asm("v_cvt_pk_bf16_f32 %0, %1, %2" : "=v"(r) : "v"(a), "v"(b)); return r;
}
// f32 -> bf16 (RNE), bits in low 16 (A-build only, once per launch)
__device__ __forceinline__ uint32_t bf16rne(float x) {
    uint32_t u = __float_as_uint(x);
    return (u + 0x7FFFu + ((u >> 16) & 1u)) >> 16;
}

// ---------------------------------------------------------------------------
// Kernel 1 (unchanged): embedding folded through input projection, gate
// exp2-scaling folded in: i/f/o rows x (-log2 e), c-row x (+2 log2 e).
// P2[bucket][h][g] = s_g * sum_e emb[bucket][e] * kernel[e][g*32 + h]
// ---------------------------------------------------------------------------
__global__ void precompute_P2_kernel(const float* __restrict__ emb,
                                     const float* __restrict__ kern,
                                     float* __restrict__ P2) {
    int idx = blockIdx.x * blockDim.x + threadIdx.x;
    if (idx >= HASH_BUCKETS * G4) return;
    int row = idx >> 7;
    int c2  = idx & 127;
    int h = c2 >> 2;
    int g = c2 & 3;
    float acc = 0.f;
#pragma unroll
    for (int e = 0; e < EMB_DIM; ++e)
        acc = fmaf(emb[row * EMB_DIM + e], kern[e * G4 + g * 32 + h], acc);
    float sg = (g == 2) ? 2.8853900817779268f : -1.4426950408889634f;
    P2[idx] = acc * sg;
}

// ---------------------------------------------------------------------------
// Kernel 2: BARRIER-FREE wave-private recurrence.
// Evidence: r9=188.6us is a barrier+LDS-roundtrip latency wall; r11 proved
// inter-block sharing serializes (310us) and r2 proved intra-block waves
// lockstep. So: delete the barrier. Each wave owns 4 batches x 32 units
// (cols = 4 batches x 4 dups; lane (b+4d, q) keeps units 8q+2d,8q+2d+1 of
// batch b -> still 2 gate-instances/lane, trans unchanged). 128 gate-rows
// via 8 MFMAs sharing one B, row-perm row(j,4q+r)->(unit 8q+j, gate r);
// lane keeps MFMAs {2d,2d+1} via cndmask tree (masks loop-invariant);
// per-lane xz rides C (even j: XZ0, odd j: XZ1 - wrong-C outputs are the
// discarded ones). Next B assembled IN-REGISTER with 4 ds_bpermute from
// same-wave lanes 16q+4i+b (no LDS memory, no barrier, no bank conflicts).
// Arithmetic is BITWISE-IDENTICAL to r9 (same fragments, same k-order,
// same gate chain) -> absmax must stay exactly 3.051758e-05.
// ---------------------------------------------------------------------------
__global__ __launch_bounds__(256)
__attribute__((amdgpu_waves_per_eu(1, 1)))
void lstm_head_kernel(const int* __restrict__ ids,
                      const float* __restrict__ P2,   // [1000][32][4], pre-scaled
                      const float* __restrict__ R,    // rec_kernel [32][128]
                      const float* __restrict__ w1,   // [32][32]
                      const float* __restrict__ b1,   // [32]
                      const float* __restrict__ w2,   // [32]
                      const float* __restrict__ b2,   // [1]
                      float* __restrict__ out) {
    __shared__ float hfin[16][33];

    const int tid  = threadIdx.x;
    const int w    = tid >> 6;        // wave 0..3
    const int lane = tid & 63;
    const int col  = lane & 15;       // MFMA column: b + 4d
    const int b    = col & 3;         // batch within wave
    const int d    = col >> 2;        // unit-pair selector (dup dimension)
    const int q    = lane >> 4;       // 0..3
    const int bb   = blockIdx.x * 16;
    const int batch = bb + 4 * w + b;
    const int u0   = 8 * q + 2 * d;   // this lane's unit pair
    const int u1   = u0 + 1;

    const float PL2E   =  2.8853900817779268f;   // 2*log2(e)
    const float NL2E   = -1.4426950408889634f;
    const float N2PL2E = -5.7707801635558536f;   // -2*PL2E

    // ---- A fragments A_j, j=0..7: lane (col,q) holds A_j[row=col][k=8q+s].
    // Row mapping: row m=4*qp+g  <->  (unit 8*qp + j, gate g); qp=col>>2=d,
    // g=col&3=b. Value = Rs[k][g*32 + 8*qp + j], k-order s=2m+e (identity,
    // matches B dword order and r9). Gate scale folded (c-gate=PL2E).
    union V8 { uint32_t u[4]; v8s v; };
    V8 A0, A1, A2, A3, A4, A5, A6, A7;
    {
        const float sg = (b == 2) ? PL2E : NL2E;
        const int gbase = b * 32 + 8 * d;
        V8* Aj[8] = { &A0, &A1, &A2, &A3, &A4, &A5, &A6, &A7 };
#pragma unroll
        for (int j = 0; j < 8; ++j) {
#pragma unroll
            for (int m = 0; m < 4; ++m) {
                uint32_t p0 = bf16rne(R[(8 * q + 2 * m)     * G4 + gbase + j] * sg);
                uint32_t p1 = bf16rne(R[(8 * q + 2 * m + 1) * G4 + gbase + j] * sg);
                Aj[j]->u[m] = p0 | (p1 << 16);
            }
        }
    }

    // ---- bpermute base address (bytes): src lane for dword i = 16q + 4i + b
    const int adr = ((lane & 0x33)) << 2;   // 64q + 4b

    // ---- loop-invariant keep-masks ----
    const bool deq0 = (d == 0), deq1 = (d == 1), deq2 = (d == 2);

    // ---- xz prefetch: contiguous 32B (units u0,u1 x 4 gates), dist-2,
    //      ping-pong E/O banks, zero moves ----
    const int* __restrict__ idrow = ids + (size_t)batch * TSTEPS;
    const float* __restrict__ baseL = P2 + 4 * u0;   // + id*G4 per step
    v4f xzE0, xzE1, xzO0, xzO1;
    {
        const float* p0 = baseL + (size_t)idrow[0] * G4;
        const float* p1 = baseL + (size_t)idrow[1] * G4;
        xzE0 = *(const v4f*)(p0);
        xzE1 = *(const v4f*)(p0 + 4);
        xzO0 = *(const v4f*)(p1);
        xzO1 = *(const v4f*)(p1 + 4);
    }
    int idE = idrow[2];
    int idO = idrow[3];

    v2f cc = {0.f, 0.f};
    v2f hv2 = {0.f, 0.f};
    uint32_t pk = 0u;   // packed bf16 {h[u0], h[u1]} — the published state

    union V8R { uint4 q; v8s v; };

#define STEP(XZ0, XZ1, IDX, T)                                                  \
    {                                                                           \
        /* B fragment: 4 in-register bpermutes of pk (prev h), identity k */    \
        int B0_ = __builtin_amdgcn_ds_bpermute(adr,      (int)pk);              \
        int B1_ = __builtin_amdgcn_ds_bpermute(adr + 16, (int)pk);              \
        int B2_ = __builtin_amdgcn_ds_bpermute(adr + 32, (int)pk);              \
        int B3_ = __builtin_amdgcn_ds_bpermute(adr + 48, (int)pk);              \
        V8R Bv;                                                                 \
        Bv.q.x = (uint32_t)B0_; Bv.q.y = (uint32_t)B1_;                         \
        Bv.q.z = (uint32_t)B2_; Bv.q.w = (uint32_t)B3_;                         \
        /* 8 MFMAs, one shared B; per-lane xz rides C (even j: XZ0, odd: XZ1;   \
           wrong-C rows are exactly the discarded ones) */                      \
        v4f o0 = __builtin_amdgcn_mfma_f32_16x16x32_bf16(A0.v, Bv.v, XZ0, 0, 0, 0); \
        v4f o1 = __builtin_amdgcn_mfma_f32_16x16x32_bf16(A1.v, Bv.v, XZ1, 0, 0, 0); \
        v4f o2 = __builtin_amdgcn_mfma_f32_16x16x32_bf16(A2.v, Bv.v, XZ0, 0, 0, 0); \
        v4f o3 = __builtin_amdgcn_mfma_f32_16x16x32_bf16(A3.v, Bv.v, XZ1, 0, 0, 0); \
        v4f o4 = __builtin_amdgcn_mfma_f32_16x16x32_bf16(A4.v, Bv.v, XZ0, 0, 0, 0); \
        v4f o5 = __builtin_amdgcn_mfma_f32_16x16x32_bf16(A5.v, Bv.v, XZ1, 0, 0, 0); \
        v4f o6 = __builtin_amdgcn_mfma_f32_16x16x32_bf16(A6.v, Bv.v, XZ0, 0, 0, 0); \
        v4f o7 = __builtin_amdgcn_mfma_f32_16x16x32_bf16(A7.v, Bv.v, XZ1, 0, 0, 0); \
        /* XZ banks consumed (C operand) -> refill same bank for t+2 */         \
        {                                                                       \
            const float* pf_ = baseL + (size_t)(IDX) * G4;                      \
            XZ0 = *(const v4f*)(pf_);                                           \
            XZ1 = *(const v4f*)(pf_ + 4);                                       \
        }                                                                       \
        { int nt_ = (T) + 4; IDX = idrow[nt_ < TSTEPS ? nt_ : (TSTEPS - 1)]; }  \
        /* keep this lane's two MFMAs: j=2d and j=2d+1 (cndmask tree) */        \
        v4f z0 = deq0 ? o0 : (deq1 ? o2 : (deq2 ? o4 : o6));                    \
        v4f z1 = deq0 ? o1 : (deq1 ? o3 : (deq2 ? o5 : o7));                    \
        /* gates: identical chain to r9 (pre-scaled z, grouped rcp pairs) */    \
        float ei0 = fexp2(z0[0]), ei1 = fexp2(z1[0]);                           \
        float ef0 = fexp2(z0[1]), ef1 = fexp2(z1[1]);                           \
        float eg0 = fexp2(z0[2]), eg1 = fexp2(z1[2]);                           \
        float eq0 = fexp2(z0[3]), eq1 = fexp2(z1[3]);                           \
        v2f di = v2f{ei0, ei1} + 1.f;                                           \
        v2f df = v2f{ef0, ef1} + 1.f;                                           \
        v2f dc = v2f{eg0, eg1} + 1.f;                                           \
        v2f dq = v2f{eq0, eq1} + 1.f;                                           \
        v2f Pp = di * df, Qq = dc * dq;                                         \
        v2f PQ = Pp * Qq;                                                       \
        float R4 = frcp(PQ.x * PQ.y);                                           \
        v2f rr; rr.x = R4 * PQ.y; rr.y = R4 * PQ.x;                             \
        v2f rP = rr * Qq, rQ = rr * Pp;                                         \
        v2f ig = rP * df, fg = rP * di, rc = rQ * dq, og = rQ * dc;             \
        v2f tz; tz.x = fmaf(N2PL2E, rc.x, PL2E);                                \
                tz.y = fmaf(N2PL2E, rc.y, PL2E);                                \
        v2f itz = ig * tz;                                                      \
        cc.x = fmaf(fg.x, cc.x, itz.x);                                         \
        cc.y = fmaf(fg.y, cc.y, itz.y);                                         \
        float ecc0 = fexp2(cc.x), ecc1 = fexp2(cc.y);                           \
        v2f dn = v2f{ecc0, ecc1} + 1.f;                                         \
        float R2 = frcp(dn.x * dn.y);                                           \
        v2f rn; rn.x = R2 * dn.y; rn.y = R2 * dn.x;                             \
        v2f m2og = og * (-2.f);                                                 \
        hv2.x = fmaf(m2og.x, rn.x, og.x);                                       \
        hv2.y = fmaf(m2og.y, rn.y, og.y);                                       \
        /* publish in-register: pack {h[u0],h[u1]} — next step bpermutes it */  \
        pk = cvtpk_bf16(hv2.x, hv2.y);                                          \
    }

    for (int t = 0; t < TSTEPS; t += 2) {
        STEP(xzE0, xzE1, idE, t)
        STEP(xzO0, xzO1, idO, t + 1)
    }
#undef STEP

    // ---- MLP head ----
    hfin[4 * w + b][u0] = hv2.x;
    hfin[4 * w + b][u1] = hv2.y;
    __syncthreads();

    int u = tid & 31;
    for (int bq = tid >> 5; bq < 16; bq += 8) {
        float y = b1[u];
#pragma unroll
        for (int k = 0; k < HDIM; ++k)
            y = fmaf(hfin[bq][k], w1[k * HDIM + u], y);
        y = fmaxf(y, 0.f);
        float vv = y * w2[u];
#pragma unroll
        for (int off = 16; off >= 1; off >>= 1)
            vv += __shfl_xor(vv, off);
        if (u == 0) out[bb + bq] = vv + b2[0];
    }
}

extern "C" void kernel_launch(void* const* d_in, const int* in_sizes, int n_in,
                              void* d_out, int out_size, void* d_ws, size_t ws_size,
                              hipStream_t stream) {
    const int*   ids  = (const int*)d_in[0];
    const float* emb  = (const float*)d_in[1];
    const float* kern = (const float*)d_in[2];
    const float* rec  = (const float*)d_in[3];
    const float* w1   = (const float*)d_in[4];
    const float* b1   = (const float*)d_in[5];
    const float* w2   = (const float*)d_in[6];
    const float* b2   = (const float*)d_in[7];
    float* out = (float*)d_out;
    float* P2  = (float*)d_ws;   // 512 KB scratch

    precompute_P2_kernel<<<(HASH_BUCKETS * G4 + 255) / 256, 256, 0, stream>>>(
        emb, kern, P2);
    lstm_head_kernel<<<BATCH / 16, 256, 0, stream>>>(
        ids, P2, rec, w1, b1, w2, b2, out);
}

// Round 13
// 243.366 us; speedup vs baseline: 1.4518x; 1.1848x over previous
//
#include <hip/hip_runtime.h>
#include <stdint.h>

#define HASH_BUCKETS 1000
#define EMB_DIM 16
#define HDIM 32
#define G4 128   // 4*HDIM
#define TSTEPS 512
#define BATCH 4096

typedef short v8s __attribute__((ext_vector_type(8)));   // 8 bf16 (4 VGPRs)
typedef float v4f __attribute__((ext_vector_type(4)));   // MFMA acc
typedef float v2f __attribute__((ext_vector_type(2)));   // packed f32 pair

__device__ __forceinline__ float frcp(float x) {
    float r; asm("v_rcp_f32 %0, %1" : "=v"(r) : "v"(x)); return r;
}
__device__ __forceinline__ float fexp2(float x) {
    float r; asm("v_exp_f32 %0, %1" : "=v"(r) : "v"(x)); return r;
}
// packed f32->bf16 (RNE): dst.lo16 = bf16(a), dst.hi16 = bf16(b)
__device__ __forceinline__ uint32_t cvtpk_bf16(float a, float b) {
    uint32_t r; asm("v_cvt_pk_bf16_f32 %0, %1, %2" : "=v"(r) : "v"(a), "v"(b)); return r;
}
// f32 -> bf16 (RNE), bits in low 16 (A-build only, once per launch)
__device__ __forceinline__ uint32_t bf16rne(float x) {
    uint32_t u = __float_as_uint(x);
    return (u + 0x7FFFu + ((u >> 16) & 1u)) >> 16;
}

// ---------------------------------------------------------------------------
// Kernel 1 (unchanged): embedding folded through input projection, gate
// exp2-scaling folded in: i/f/o rows x (-log2 e), c-row x (+2 log2 e).
// P2[bucket][h][g] = s_g * sum_e emb[bucket][e] * kernel[e][g*32 + h]
// ---------------------------------------------------------------------------
__global__ void precompute_P2_kernel(const float* __restrict__ emb,
                                     const float* __restrict__ kern,
                                     float* __restrict__ P2) {
    int idx = blockIdx.x * blockDim.x + threadIdx.x;
    if (idx >= HASH_BUCKETS * G4) return;
    int row = idx >> 7;
    int c2  = idx & 127;
    int h = c2 >> 2;
    int g = c2 & 3;
    float acc = 0.f;
#pragma unroll
    for (int e = 0; e < EMB_DIM; ++e)
        acc = fmaf(emb[row * EMB_DIM + e], kern[e * G4 + g * 32 + h], acc);
    float sg = (g == 2) ? 2.8853900817779268f : -1.4426950408889634f;
    P2[idx] = acc * sg;
}

// ---------------------------------------------------------------------------
// Kernel 2: r9 champion structure (188.6us steady; proven optimal
// decomposition by r2/r3/r11/r12 exclusion), with the gate algebra
// UNGROUPED this round:
//   ig=1/di, fg=1/df, rc=1/dc, og=1/dq are four independent sigmoids ->
//   direct v_rcp_f32 each. The r7-era grouped-reciprocal (1 rcp + cross
//   muls) saved trans ISSUE when issue was binding, but puts ~5 extra
//   levels (Pp*Qq->PQ->rcp->rQ->rc) on the c-critical path and ~2 levels
//   (pair product) on the tanh tail right before pack->write->barrier.
//   Now the step is latency-bound (VALUBusy 29%), so: shorter chain
//   (-30..55 cyc) for +10 trans ops (+80..160 issue, fits in stalls).
//   Fewer roundings -> absmax same or better. c-gate exp2 ordered first.
// Everything else byte-identical to r9.
// ---------------------------------------------------------------------------
__global__ __launch_bounds__(256)
__attribute__((amdgpu_waves_per_eu(1, 1)))
void lstm_head_kernel(const int* __restrict__ ids,
                      const float* __restrict__ P2,   // [1000][32][4], pre-scaled
                      const float* __restrict__ R,    // rec_kernel [32][128]
                      const float* __restrict__ w1,   // [32][32]
                      const float* __restrict__ b1,   // [32]
                      const float* __restrict__ w2,   // [32]
                      const float* __restrict__ b2,   // [1]
                      float* __restrict__ out) {
    // per col row: hi dwords [0..15] | (legacy lo region, unused) | pad
    __shared__ __align__(16) uint32_t hbuf[2][16][36];
    __shared__ float hfin[16][33];

    const int tid  = threadIdx.x;
    const int w    = tid >> 6;        // wave 0..3
    const int lane = tid & 63;
    const int col  = lane & 15;       // batch within group
    const int quad = lane >> 4;       // 0..3
    const int bb   = blockIdx.x * 16;
    const int u0   = 8 * w + 2 * quad;   // adjacent unit pair
    const int u1   = u0 + 1;

    const float PL2E   =  2.8853900817779268f;   // 2*log2(e)
    const float NL2E   = -1.4426950408889634f;
    const float N2PL2E = -5.7707801635558536f;   // -2*PL2E

    // ---- A fragments, plain bf16-RNE (identity k-order: s=2r+e <-> k=8q+s) ----
    union V8 { uint32_t u[4]; v8s v; };
    V8 A0, A1;
    {
        int tt = col >> 2, g = col & 3;
        float sg = (g == 2) ? PL2E : NL2E;
        int gc0 = g * 32 + 8 * w + 2 * tt;
        int gc1 = gc0 + 1;
#pragma unroll
        for (int r = 0; r < 4; ++r) {
            uint32_t h0p[2], h1p[2];
#pragma unroll
            for (int e = 0; e < 2; ++e) {
                int k = quad * 8 + 2 * r + e;
                h0p[e] = bf16rne(R[k * G4 + gc0] * sg);
                h1p[e] = bf16rne(R[k * G4 + gc1] * sg);
            }
            A0.u[r] = h0p[0] | (h0p[1] << 16);
            A1.u[r] = h1p[0] | (h1p[1] << 16);
        }
    }

    for (int i = tid; i < 2 * 16 * 36; i += 256)
        ((uint32_t*)hbuf)[i] = 0u;

    // ---- loop-invariant LDS addresses (conflict-free by analysis) ----
    const uint32_t* rd[2] = { &hbuf[0][col][4 * quad],
                              &hbuf[1][col][4 * quad] };      // Bhi
    uint32_t* wr[2] = { &hbuf[1][col][4 * w + quad],
                        &hbuf[0][col][4 * w + quad] };        // hi

    // ---- xz prefetch: contiguous 32B (units u0,u1 x 4 gates), dist-2,
    //      ping-pong E/O banks, zero moves ----
    const int* __restrict__ idrow = ids + (size_t)(bb + col) * TSTEPS;
    const float* __restrict__ baseL = P2 + 4 * u0;   // + id*G4 per step
    v4f xzE0, xzE1, xzO0, xzO1;
    {
        const float* p0 = baseL + (size_t)idrow[0] * G4;
        const float* p1 = baseL + (size_t)idrow[1] * G4;
        xzE0 = *(const v4f*)(p0);
        xzE1 = *(const v4f*)(p0 + 4);
        xzO0 = *(const v4f*)(p1);
        xzO1 = *(const v4f*)(p1 + 4);
    }
    int idE = idrow[2];
    int idO = idrow[3];

    v2f cc = {0.f, 0.f};
    v2f hv2 = {0.f, 0.f};

    __syncthreads();

    union V8R { uint4 q; v8s v; };

#define STEP(PB, XZ0, XZ1, IDX, T)                                              \
    {                                                                           \
        /* B fragment: ONE b128 read IS Bhi (identity k-order) */               \
        V8R Bhi;                                                                \
        Bhi.q = *(const uint4*)(rd[PB]);                                        \
        /* z = R^T h + xz in ONE MFMA per unit (xz rides the C operand) */      \
        v4f z0 = __builtin_amdgcn_mfma_f32_16x16x32_bf16(A0.v, Bhi.v, XZ0, 0, 0, 0); \
        v4f z1 = __builtin_amdgcn_mfma_f32_16x16x32_bf16(A1.v, Bhi.v, XZ1, 0, 0, 0); \
        /* xz banks consumed above -> refill same bank for t+2 (no moves) */    \
        {                                                                       \
            const float* pf_ = baseL + (size_t)(IDX) * G4;                      \
            XZ0 = *(const v4f*)(pf_);                                           \
            XZ1 = *(const v4f*)(pf_ + 4);                                       \
        }                                                                       \
        { int nt_ = (T) + 4; IDX = idrow[nt_ < TSTEPS ? nt_ : (TSTEPS - 1)]; }  \
        /* gates: direct per-gate sigmoids (c-path first). Pre-scaled z:       \
           sigma = rcp(1 + exp2(z')); tanh(zc) = fma(N2PL2E, rcp(1+exp2), PL2E) \
           in the PL2E domain. Shortest z->cc->pack chain. */                   \
        float eg0 = fexp2(z0[2]), eg1 = fexp2(z1[2]);   /* c-gate first */      \
        float ei0 = fexp2(z0[0]), ei1 = fexp2(z1[0]);                           \
        float ef0 = fexp2(z0[1]), ef1 = fexp2(z1[1]);                           \
        float eq0 = fexp2(z0[3]), eq1 = fexp2(z1[3]);                           \
        v2f dc = v2f{eg0, eg1} + 1.f;                                           \
        v2f di = v2f{ei0, ei1} + 1.f;                                           \
        v2f df = v2f{ef0, ef1} + 1.f;                                           \
        v2f dq = v2f{eq0, eq1} + 1.f;                                           \
        v2f rc; rc.x = frcp(dc.x); rc.y = frcp(dc.y);                           \
        v2f ig; ig.x = frcp(di.x); ig.y = frcp(di.y);                           \
        v2f fg; fg.x = frcp(df.x); fg.y = frcp(df.y);                           \
        v2f og; og.x = frcp(dq.x); og.y = frcp(dq.y);                           \
        v2f tz; tz.x = fmaf(N2PL2E, rc.x, PL2E);                                \
                tz.y = fmaf(N2PL2E, rc.y, PL2E);                                \
        v2f itz = ig * tz;                                                      \
        cc.x = fmaf(fg.x, cc.x, itz.x);                                         \
        cc.y = fmaf(fg.y, cc.y, itz.y);                                         \
        float ecc0 = fexp2(cc.x), ecc1 = fexp2(cc.y);                           \
        v2f dn = v2f{ecc0, ecc1} + 1.f;                                         \
        v2f rn; rn.x = frcp(dn.x); rn.y = frcp(dn.y);                           \
        v2f m2og = og * (-2.f);   /* off-chain (og ready early) */              \
        hv2.x = fmaf(m2og.x, rn.x, og.x);                                       \
        hv2.y = fmaf(m2og.y, rn.y, og.y);                                       \
        /* publish h as plain bf16 pair: ONE cvt_pk + ONE ds_write_b32 */       \
        wr[PB][0] = cvtpk_bf16(hv2.x, hv2.y);                                   \
        /* raw barrier: LDS drain only (xz loads live across it) */             \
        asm volatile("s_waitcnt lgkmcnt(0)\n\ts_barrier" ::: "memory");         \
    }

    for (int t = 0; t < TSTEPS; t += 2) {
        STEP(0, xzE0, xzE1, idE, t)
        STEP(1, xzO0, xzO1, idO, t + 1)
    }
#undef STEP

    // ---- MLP head ----
    hfin[col][u0] = hv2.x;
    hfin[col][u1] = hv2.y;
    __syncthreads();

    int u = tid & 31;
    for (int bq = tid >> 5; bq < 16; bq += 8) {
        float y = b1[u];
#pragma unroll
        for (int k = 0; k < HDIM; ++k)
            y = fmaf(hfin[bq][k], w1[k * HDIM + u], y);
        y = fmaxf(y, 0.f);
        float vv = y * w2[u];
#pragma unroll
        for (int off = 16; off >= 1; off >>= 1)
            vv += __shfl_xor(vv, off);
        if (u == 0) out[bb + bq] = vv + b2[0];
    }
}

extern "C" void kernel_launch(void* const* d_in, const int* in_sizes, int n_in,
                              void* d_out, int out_size, void* d_ws, size_t ws_size,
                              hipStream_t stream) {
    const int*   ids  = (const int*)d_in[0];
    const float* emb  = (const float*)d_in[1];
    const float* kern = (const float*)d_in[2];
    const float* rec  = (const float*)d_in[3];
    const float* w1   = (const float*)d_in[4];
    const float* b1   = (const float*)d_in[5];
    const float* w2   = (const float*)d_in[6];
    const float* b2   = (const float*)d_in[7];
    float* out = (float*)d_out;
    float* P2  = (float*)d_ws;   // 512 KB scratch

    precompute_P2_kernel<<<(HASH_BUCKETS * G4 + 255) / 256, 256, 0, stream>>>(
        emb, kern, P2);
    lstm_head_kernel<<<BATCH / 16, 256, 0, stream>>>(
        ids, P2, rec, w1, b1, w2, b2, out);
}